// Round 9
// baseline (294.638 us; speedup 1.0000x reference)
//
#include <hip/hip_runtime.h>

constexpr int KDIM  = 256;   // input feature dim
constexpr int HDIM  = 128;   // output feature dim
constexpr int BK    = 128;   // nodes per coarse bucket (col>>7)
constexpr int CHUNK = 8192;  // edges per sort block
constexpr int NBMAX = 800;   // max coarse buckets (N<=102400)

typedef __bf16 bf16x8 __attribute__((ext_vector_type(8)));
typedef float  f32x4  __attribute__((ext_vector_type(4)));

__device__ __forceinline__ ushort f2bf(float f) {
    unsigned u = __float_as_uint(f);
    unsigned r = (u + 0x7fffu + ((u >> 16) & 1u)) >> 16;   // RNE
    return (ushort)r;
}

// dequant-accumulate 8 int8 channels (uint2) with per-row scale s
__device__ __forceinline__ void acc8i(float* a, uint2 u, float s) {
    int x = (int)u.x, y = (int)u.y;
    a[0] += s * (float)((x << 24) >> 24);
    a[1] += s * (float)((x << 16) >> 24);
    a[2] += s * (float)((x <<  8) >> 24);
    a[3] += s * (float)( x        >> 24);
    a[4] += s * (float)((y << 24) >> 24);
    a[5] += s * (float)((y << 16) >> 24);
    a[6] += s * (float)((y <<  8) >> 24);
    a[7] += s * (float)( y        >> 24);
}

// ---------------- fused: prep Wt (blocks 0..7), zero row + hscale[n] (8),
// block-local bucket sort (9..). R2-proven structure. ----------------
__global__ __launch_bounds__(512) void prep_sort_kernel(
    const float* __restrict__ W, ushort* __restrict__ Wt, char* __restrict__ hsb8,
    float* __restrict__ hscale,
    const int* __restrict__ row, const int* __restrict__ col,
    uint* __restrict__ ebuf, int* __restrict__ histG, int* __restrict__ localOff,
    int n, int e, int nbv, int gblk) {
    __shared__ uint dst[CHUNK];          // 32 KB
    __shared__ int hist[NBMAX], excl[NBMAX], cur[NBMAX];
    __shared__ int ws2[8];
    int b = blockIdx.x, t = threadIdx.x;
    if (b < 8) {
        // Wt frag layout: g=(c*8+nf)*64+lane holds 8 contiguous-k bf16
        int g = b * 512 + t;
        int lane = g & 63, cn = g >> 6;
        int c = cn >> 3, nf = cn & 7;
        int ncol = nf * 16 + (lane & 15);
        int k0 = c * 32 + (lane >> 4) * 8;
        ushort* dp = Wt + (size_t)g * 8;
        #pragma unroll
        for (int j = 0; j < 8; ++j) dp[j] = f2bf(W[(k0 + j) * HDIM + ncol]);
        return;
    }
    if (b == 8) {
        if (t < 32) ((uint*)(hsb8 + (size_t)n * HDIM))[t] = 0;   // zero row
        if (t == 32) hscale[n] = 0.f;                            // zero scale
        return;
    }
    int g = b - 9;                       // sort-block id
    int lane = t & 63, w = t >> 6;
    for (int i = t; i < nbv; i += 512) hist[i] = 0;
    __syncthreads();
    int lo = g * CHUNK, hi = min(lo + CHUNK, e);
    int colr[16];
    #pragma unroll
    for (int k = 0; k < 4; ++k) {
        int i0 = lo + (k * 512 + t) * 4;
        if (i0 + 3 < hi) {
            int4 c4 = *(const int4*)(col + i0);
            colr[k * 4 + 0] = c4.x; colr[k * 4 + 1] = c4.y;
            colr[k * 4 + 2] = c4.z; colr[k * 4 + 3] = c4.w;
            atomicAdd(&hist[c4.x >> 7], 1); atomicAdd(&hist[c4.y >> 7], 1);
            atomicAdd(&hist[c4.z >> 7], 1); atomicAdd(&hist[c4.w >> 7], 1);
        } else {
            #pragma unroll
            for (int j = 0; j < 4; ++j) {
                int i = i0 + j;
                int c = (i < hi) ? col[i] : -1;
                colr[k * 4 + j] = c;
                if (c >= 0) atomicAdd(&hist[c >> 7], 1);
            }
        }
    }
    __syncthreads();
    // LDS exclusive scan of nbv bins (thread t owns bins [2t, 2t+2))
    {
        int b0 = t * 2;
        int h0 = (b0 < nbv) ? hist[b0] : 0;
        int h1 = (b0 + 1 < nbv) ? hist[b0 + 1] : 0;
        int s = h0 + h1, incl = s;
        #pragma unroll
        for (int d = 1; d < 64; d <<= 1) { int u = __shfl_up(incl, d, 64); if (lane >= d) incl += u; }
        if (lane == 63) ws2[w] = incl;
        __syncthreads();
        int add = 0;
        #pragma unroll
        for (int i = 0; i < 8; ++i) if (i < w) add += ws2[i];
        int run = add + incl - s;
        if (b0 < nbv)     { excl[b0] = run;          cur[b0] = run; }
        if (b0 + 1 < nbv) { excl[b0 + 1] = run + h0; cur[b0 + 1] = run + h0; }
    }
    __syncthreads();
    // place into LDS (packed: row<<7 | col&127), col from registers
    #pragma unroll
    for (int k = 0; k < 4; ++k) {
        int i0 = lo + (k * 512 + t) * 4;
        if (i0 + 3 < hi) {
            int4 r4 = *(const int4*)(row + i0);
            int rr[4] = {r4.x, r4.y, r4.z, r4.w};
            #pragma unroll
            for (int j = 0; j < 4; ++j) {
                int c = colr[k * 4 + j];
                int p = atomicAdd(&cur[c >> 7], 1);
                dst[p] = ((uint)rr[j] << 7) | (uint)(c & 127);
            }
        } else {
            #pragma unroll
            for (int j = 0; j < 4; ++j) {
                int i = i0 + j, c = colr[k * 4 + j];
                if (c >= 0) {
                    int p = atomicAdd(&cur[c >> 7], 1);
                    dst[p] = ((uint)row[i] << 7) | (uint)(c & 127);
                }
            }
        }
    }
    __syncthreads();
    int cnt = hi - lo;
    for (int k = 0; k < 4; ++k) {                      // coalesced uint4 write-out
        int i0 = (k * 512 + t) * 4;
        if (i0 + 3 < cnt) *(uint4*)(ebuf + lo + i0) = *(uint4*)&dst[i0];
        else for (int j = 0; j < 4; ++j) if (i0 + j < cnt) ebuf[lo + i0 + j] = dst[i0 + j];
    }
    for (int i = t; i < nbv; i += 512) {
        histG[i * gblk + g]    = hist[i];
        localOff[i * gblk + g] = excl[i];
    }
}

// ---------------- GEMM: hsb8 = int8( x @ W / rowscale ), hscale = rowmax/127.
// dinv NOT applied here: degscale folds rsqrt(deg+1) into hscale afterwards. ----------------

constexpr int MT = 64;
constexpr int XS_STRIDE = 264;

__global__ __launch_bounds__(256) void gemm_kernel(const float* __restrict__ x,
                                                   const ushort* __restrict__ Wt,
                                                   char* __restrict__ hsb8,
                                                   float* __restrict__ hscale, int n) {
    __shared__ ushort xs[MT * XS_STRIDE];
    __shared__ uint rmaxs[16];
    int t = threadIdx.x, lane = t & 63, w = t >> 6;
    int row0 = blockIdx.x * MT;

    bf16x8 bfrag[8][2];
    #pragma unroll
    for (int c = 0; c < 8; ++c)
        #pragma unroll
        for (int f = 0; f < 2; ++f)
            bfrag[c][f] = *(const bf16x8*)(Wt + (size_t)(((c * 8) + (w * 2 + f)) * 64 + lane) * 8);

    #pragma unroll
    for (int i = 0; i < 16; ++i) {
        int rl = w * 16 + i;
        int gr = row0 + rl; if (gr >= n) gr = n - 1;
        float4 v = *(const float4*)(x + (size_t)gr * KDIM + lane * 4);
        ushort4 o;
        o.x = f2bf(v.x); o.y = f2bf(v.y); o.z = f2bf(v.z); o.w = f2bf(v.w);
        *(ushort4*)(xs + rl * XS_STRIDE + lane * 4) = o;
    }
    __syncthreads();

    for (int s = 0; s < MT / 16; ++s) {
        f32x4 acc0 = {0.f, 0.f, 0.f, 0.f}, acc1 = {0.f, 0.f, 0.f, 0.f};
        #pragma unroll
        for (int c = 0; c < 8; ++c) {
            const ushort* ap = xs + (s * 16 + (lane & 15)) * XS_STRIDE + c * 32 + (lane >> 4) * 8;
            bf16x8 afrag = *(const bf16x8*)ap;
            acc0 = __builtin_amdgcn_mfma_f32_16x16x32_bf16(afrag, bfrag[c][0], acc0, 0, 0, 0);
            acc1 = __builtin_amdgcn_mfma_f32_16x16x32_bf16(afrag, bfrag[c][1], acc1, 0, 0, 0);
        }
        // ---- per-row absmax reduction ----
        if (t < 16) rmaxs[t] = 0;
        __syncthreads();
        #pragma unroll
        for (int reg = 0; reg < 4; ++reg) {
            int rl = s * 16 + (lane >> 4) * 4 + reg;
            int gr = row0 + rl;
            if (gr < n) {
                float m = fmaxf(fabsf(acc0[reg]), fabsf(acc1[reg]));
                atomicMax(&rmaxs[(lane >> 4) * 4 + reg], __float_as_uint(m));
            }
        }
        __syncthreads();
        // ---- quantize + store ----
        #pragma unroll
        for (int reg = 0; reg < 4; ++reg) {
            int rl = s * 16 + (lane >> 4) * 4 + reg;
            int gr = row0 + rl;
            if (gr < n) {
                float rm = __uint_as_float(rmaxs[(lane >> 4) * 4 + reg]);
                float inv = (rm > 0.f) ? 127.f / rm : 0.f;
                int q0 = __float2int_rn(acc0[reg] * inv);
                int q1 = __float2int_rn(acc1[reg] * inv);
                int col0 = w * 32 + (lane & 15);
                hsb8[(size_t)gr * HDIM + col0]      = (char)q0;
                hsb8[(size_t)gr * HDIM + col0 + 16] = (char)q1;
            }
        }
        if (t < 16) {
            int gr = row0 + s * 16 + t;
            if (gr < n) hscale[gr] = __uint_as_float(rmaxs[t]) * (1.f / 127.f);
        }
        __syncthreads();
    }
}

// ---------------- degscale: per-bucket deg hist over ebuf runs ->
// hscale[node] *= rsqrt(deg+1). No placement, no scan, no output lists. ----------------
__global__ __launch_bounds__(256) void degscale_kernel(
    const uint* __restrict__ ebuf, const int* __restrict__ histG,
    const int* __restrict__ localOff, float* __restrict__ hscale,
    int n, int gblk) {
    __shared__ int hist[BK];
    int b = blockIdx.x, t = threadIdx.x;
    if (t < BK) hist[t] = 0;
    __syncthreads();
    int grp = t >> 4, li = t & 15;
    for (int g = grp; g < gblk; g += 16) {
        int c   = histG[b * gblk + g];
        int src = g * CHUNK + localOff[b * gblk + g];
        for (int i = li; i < c; i += 16) atomicAdd(&hist[ebuf[src + i] & 127], 1);
    }
    __syncthreads();
    if (t < BK) {
        int node = b * BK + t;
        if (node < n) hscale[node] *= rsqrtf((float)(hist[t] + 1));
    }
}

// ---------------- agg: fused fine-sort + int8 gather-accumulate ----------------
// One block per 128-node bucket: segment-count scan -> gather runs from ebuf ->
// LDS counting sort (csrl) -> 16 groups x 16 lanes, 8 nodes/group, 8-deep batches.
// dc = rsqrt(deg+1) from own hist; per-edge scale via hscale (has dinv folded in).
__global__ __launch_bounds__(256) void agg_kernel(
    const char* __restrict__ hsb8, const float* __restrict__ hscale,
    const uint* __restrict__ ebuf, const int* __restrict__ histG,
    const int* __restrict__ localOff, const float* __restrict__ bias,
    const float* __restrict__ alpha, float* __restrict__ out, int n, int gblk) {
    __shared__ uint elist[4096];
    __shared__ uint csrl[4096];
    __shared__ int hist[BK], excl[BK], cur[BK];
    __shared__ int segOff[256];                     // gblk <= 256
    int b = blockIdx.x, t = threadIdx.x;

    segOff[t] = (t < gblk) ? histG[b * gblk + t] : 0;
    if (t < BK) { hist[t] = 0; cur[t] = 0; }
    __syncthreads();
    // inclusive Hillis-Steele scan over 256 segment counts
    for (int d = 1; d < 256; d <<= 1) {
        int v = (t >= d) ? segOff[t - d] : 0;
        __syncthreads();
        segOff[t] += v;
        __syncthreads();
    }
    int cnt = min(segOff[255], 4096);
    // gather this bucket's per-block runs into LDS, 16-lane group per run
    int grp = t >> 4, li = t & 15;
    for (int g = grp; g < gblk; g += 16) {
        int pre = (g == 0) ? 0 : min(segOff[g - 1], 4096);
        int end = min(segOff[g], 4096);
        int c   = end - pre;
        int src = g * CHUNK + localOff[b * gblk + g];
        for (int i = li; i < c; i += 16) elist[pre + i] = ebuf[src + i];
    }
    __syncthreads();
    for (int i = t; i < cnt; i += 256) atomicAdd(&hist[elist[i] & 127], 1);
    __syncthreads();
    if (t < 64) {                       // exclusive scan of 128 bins, wave 0
        int v0 = hist[2 * t], v1 = hist[2 * t + 1];
        int s = v0 + v1, incl = s;
        #pragma unroll
        for (int d = 1; d < 64; d <<= 1) { int u = __shfl_up(incl, d, 64); if (t >= d) incl += u; }
        int base = incl - s;
        excl[2 * t] = base; excl[2 * t + 1] = base + v0;
    }
    __syncthreads();
    for (int i = t; i < cnt; i += 256) {
        uint v = elist[i];
        int d = v & 127;
        int r = atomicAdd(&cur[d], 1);
        csrl[excl[d] + r] = v >> 7;
    }
    __syncthreads();

    const uint2* hs2 = (const uint2*)hsb8;  // row = 16 x uint2, lane li owns 8 ch
    for (int nl = grp; nl < BK; nl += 16) {            // 8 nodes per group
        int node = b * BK + nl;
        bool valid = node < n;
        int nd   = valid ? node : n;        // n = zero row (scale 0)
        int base = excl[nl];
        int c    = hist[nl];                // 0 for out-of-range nodes

        float a[8];
        #pragma unroll
        for (int i = 0; i < 8; ++i) a[i] = 0.f;

        uint2 su = hs2[(size_t)nd * 16 + li];   // self loop
        acc8i(a, su, hscale[nd]);

        for (int it = 0; it < c; it += 8) {
            int s[8];
            #pragma unroll
            for (int k = 0; k < 8; ++k)
                s[k] = (it + k < c) ? (int)csrl[base + it + k] : n;   // LDS broadcast
            uint2 u[8];
            float sc[8];
            #pragma unroll
            for (int k = 0; k < 8; ++k) u[k] = hs2[(size_t)s[k] * 16 + li];
            #pragma unroll
            for (int k = 0; k < 8; ++k) sc[k] = hscale[s[k]];
            #pragma unroll
            for (int k = 0; k < 8; ++k) acc8i(a, u[k], sc[k]);
        }

        if (valid) {
            float dc = rsqrtf((float)(c + 1));
            int c0 = li * 8;
            float o[8];
            #pragma unroll
            for (int i = 0; i < 8; ++i) {
                float v = fmaf(dc, a[i], bias[c0 + i]);
                o[i] = v >= 0.f ? v : alpha[c0 + i] * v;
            }
            float* op = out + (size_t)node * HDIM + c0;
            f32x4 v0 = {o[0], o[1], o[2], o[3]};
            f32x4 v1 = {o[4], o[5], o[6], o[7]};
            __builtin_nontemporal_store(v0, (f32x4*)op);
            __builtin_nontemporal_store(v1, (f32x4*)(op + 4));
        }
    }
}

// ---------------- launch ----------------

extern "C" void kernel_launch(void* const* d_in, const int* in_sizes, int n_in,
                              void* d_out, int out_size, void* d_ws, size_t ws_size,
                              hipStream_t stream) {
    const float* x     = (const float*)d_in[0];
    const int*   ei    = (const int*)d_in[1];
    const float* W     = (const float*)d_in[2];
    const float* b     = (const float*)d_in[3];
    const float* alpha = (const float*)d_in[4];
    float* out = (float*)d_out;

    int E = in_sizes[1] / 2;
    int N = in_sizes[0] / KDIM;
    int NB = (N + BK - 1) / BK;                // coarse buckets (782)
    int GBLK = (E + CHUNK - 1) / CHUNK;        // sort blocks (196)
    int SCAN_N = NB * GBLK;

    // ws: hsb8 int8[(N+1)*128] | hscale f32[N+1] | Wt bf16[32768]
    //   | histG int[SCAN_N] | localOff int[SCAN_N] | ebuf uint[GBLK*CHUNK]
    char*  hsb8   = (char*)d_ws;
    float* hscale = (float*)(hsb8 + (size_t)(N + 1) * HDIM);
    ushort* Wt    = (ushort*)(hscale + (N + 1));
    int* histG    = (int*)(Wt + 32768);
    int* localOff = histG + SCAN_N;
    uint* ebuf    = (uint*)(localOff + SCAN_N);

    const int* rowp = ei;      // sources
    const int* colp = ei + E;  // destinations

    hipLaunchKernelGGL(prep_sort_kernel, dim3(9 + GBLK), dim3(512), 0, stream,
                       W, Wt, hsb8, hscale, rowp, colp, ebuf, histG, localOff, N, E, NB, GBLK);
    hipLaunchKernelGGL(gemm_kernel, dim3((N + MT - 1) / MT), dim3(256), 0, stream,
                       x, Wt, hsb8, hscale, N);
    hipLaunchKernelGGL(degscale_kernel, dim3(NB), dim3(256), 0, stream,
                       ebuf, histG, localOff, hscale, N, GBLK);
    hipLaunchKernelGGL(agg_kernel, dim3(NB), dim3(256), 0, stream,
                       hsb8, hscale, ebuf, histG, localOff, b, alpha, out, N, GBLK);
}

// Round 10
// 279.193 us; speedup vs baseline: 1.0553x; 1.0553x over previous
//
#include <hip/hip_runtime.h>

constexpr int KDIM  = 256;   // input feature dim
constexpr int HDIM  = 128;   // output feature dim
constexpr int BK    = 128;   // nodes per coarse bucket (col>>7)
constexpr int CHUNK = 8192;  // edges per sort block
constexpr int NBMAX = 800;   // max coarse buckets (N<=102400)

typedef __bf16 bf16x8 __attribute__((ext_vector_type(8)));
typedef float  f32x4  __attribute__((ext_vector_type(4)));

__device__ __forceinline__ ushort f2bf(float f) {
    __bf16 h = (__bf16)f;                       // RNE, v_cvt_pk_bf16_f32
    return __builtin_bit_cast(unsigned short, h);
}

// dequant-accumulate 8 int8 channels (uint2) with per-row scale s
__device__ __forceinline__ void acc8i(float* a, uint2 u, float s) {
    int x = (int)u.x, y = (int)u.y;
    a[0] += s * (float)((x << 24) >> 24);
    a[1] += s * (float)((x << 16) >> 24);
    a[2] += s * (float)((x <<  8) >> 24);
    a[3] += s * (float)( x        >> 24);
    a[4] += s * (float)((y << 24) >> 24);
    a[5] += s * (float)((y << 16) >> 24);
    a[6] += s * (float)((y <<  8) >> 24);
    a[7] += s * (float)( y        >> 24);
}

// ---------------- fused: prep Wt (blocks 0..7), zero row (8), block-local
// bucket sort (9..). Rank-based: ONE LDS-atomic pass (rank), scan, plain placement. ----------------
__global__ __launch_bounds__(512) void prep_sort_kernel(
    const float* __restrict__ W, ushort* __restrict__ Wt, char* __restrict__ hsb8,
    float* __restrict__ hscale,
    const int* __restrict__ row, const int* __restrict__ col,
    uint* __restrict__ ebuf, int* __restrict__ histG, int* __restrict__ localOff,
    int n, int e, int nbv, int gblk) {
    __shared__ uint dst[CHUNK];          // 32 KB
    __shared__ int cnt[NBMAX], excl[NBMAX];
    __shared__ int ws2[8];
    int b = blockIdx.x, t = threadIdx.x;
    if (b < 8) {
        // Wt frag layout: g=(c*8+nf)*64+lane holds 8 contiguous-k bf16
        int g = b * 512 + t;
        int lane = g & 63, cn = g >> 6;
        int c = cn >> 3, nf = cn & 7;
        int ncol = nf * 16 + (lane & 15);
        int k0 = c * 32 + (lane >> 4) * 8;
        ushort* dp = Wt + (size_t)g * 8;
        #pragma unroll
        for (int j = 0; j < 8; ++j) dp[j] = f2bf(W[(k0 + j) * HDIM + ncol]);
        return;
    }
    if (b == 8) {
        if (t < 32) ((uint*)(hsb8 + (size_t)n * HDIM))[t] = 0;   // zero row
        if (t == 32) hscale[n] = 0.f;                            // zero scale
        return;
    }
    int g = b - 9;                       // sort-block id
    int lane = t & 63, w = t >> 6;
    for (int i = t; i < nbv; i += 512) cnt[i] = 0;
    __syncthreads();
    int lo = g * CHUNK, hi = min(lo + CHUNK, e);
    int colr[16], rowr[16], rank[16];
    // pass 1: load row+col, take rank via single LDS atomic per edge
    #pragma unroll
    for (int k = 0; k < 4; ++k) {
        int i0 = lo + (k * 512 + t) * 4;
        if (i0 + 3 < hi) {
            int4 c4 = *(const int4*)(col + i0);
            int4 r4 = *(const int4*)(row + i0);
            colr[k * 4 + 0] = c4.x; colr[k * 4 + 1] = c4.y;
            colr[k * 4 + 2] = c4.z; colr[k * 4 + 3] = c4.w;
            rowr[k * 4 + 0] = r4.x; rowr[k * 4 + 1] = r4.y;
            rowr[k * 4 + 2] = r4.z; rowr[k * 4 + 3] = r4.w;
            rank[k * 4 + 0] = atomicAdd(&cnt[c4.x >> 7], 1);
            rank[k * 4 + 1] = atomicAdd(&cnt[c4.y >> 7], 1);
            rank[k * 4 + 2] = atomicAdd(&cnt[c4.z >> 7], 1);
            rank[k * 4 + 3] = atomicAdd(&cnt[c4.w >> 7], 1);
        } else {
            #pragma unroll
            for (int j = 0; j < 4; ++j) {
                int i = i0 + j;
                int c = (i < hi) ? col[i] : -1;
                colr[k * 4 + j] = c;
                rowr[k * 4 + j] = (i < hi) ? row[i] : 0;
                if (c >= 0) rank[k * 4 + j] = atomicAdd(&cnt[c >> 7], 1);
            }
        }
    }
    __syncthreads();
    // LDS exclusive scan of nbv bins (thread t owns bins [2t, 2t+2))
    {
        int b0 = t * 2;
        int h0 = (b0 < nbv) ? cnt[b0] : 0;
        int h1 = (b0 + 1 < nbv) ? cnt[b0 + 1] : 0;
        int s = h0 + h1, incl = s;
        #pragma unroll
        for (int d = 1; d < 64; d <<= 1) { int u = __shfl_up(incl, d, 64); if (lane >= d) incl += u; }
        if (lane == 63) ws2[w] = incl;
        __syncthreads();
        int add = 0;
        #pragma unroll
        for (int i = 0; i < 8; ++i) if (i < w) add += ws2[i];
        int run = add + incl - s;
        if (b0 < nbv)     excl[b0] = run;
        if (b0 + 1 < nbv) excl[b0 + 1] = run + h0;
    }
    __syncthreads();
    // pass 2: place into LDS WITHOUT atomics (packed: row<<7 | col&127)
    #pragma unroll
    for (int k = 0; k < 4; ++k) {
        #pragma unroll
        for (int j = 0; j < 4; ++j) {
            int c = colr[k * 4 + j];
            if (c >= 0)
                dst[excl[c >> 7] + rank[k * 4 + j]] =
                    ((uint)rowr[k * 4 + j] << 7) | (uint)(c & 127);
        }
    }
    __syncthreads();
    int cntE = hi - lo;
    for (int k = 0; k < 4; ++k) {                      // coalesced uint4 write-out
        int i0 = (k * 512 + t) * 4;
        if (i0 + 3 < cntE) *(uint4*)(ebuf + lo + i0) = *(uint4*)&dst[i0];
        else for (int j = 0; j < 4; ++j) if (i0 + j < cntE) ebuf[lo + i0 + j] = dst[i0 + j];
    }
    for (int i = t; i < nbv; i += 512) {
        histG[i * gblk + g]    = cnt[i];
        localOff[i * gblk + g] = excl[i];
    }
}

// ---------------- hierarchical scan (generic) ----------------
__global__ __launch_bounds__(256) void scanA_kernel(const int* __restrict__ in,
                                                    int* __restrict__ partial, int n) {
    int t = threadIdx.x, base = blockIdx.x * 1024;
    int s = 0;
    #pragma unroll
    for (int j = 0; j < 4; ++j) {
        int i = base + j * 256 + t;
        if (i < n) s += in[i];
    }
    __shared__ int ws[4];
    #pragma unroll
    for (int d = 1; d < 64; d <<= 1) s += __shfl_xor(s, d, 64);
    int lane = t & 63, w = t >> 6;
    if (lane == 0) ws[w] = s;
    __syncthreads();
    if (t == 0) partial[blockIdx.x] = ws[0] + ws[1] + ws[2] + ws[3];
}

__global__ void scanB_kernel(int* __restrict__ partial, int nb) {  // nb <= 256, 1 block
    int t = threadIdx.x;
    int v = (t < nb) ? partial[t] : 0;
    int orig = v;
    int lane = t & 63, w = t >> 6;
    #pragma unroll
    for (int d = 1; d < 64; d <<= 1) { int u = __shfl_up(v, d, 64); if (lane >= d) v += u; }
    __shared__ int ws[4];
    if (lane == 63) ws[w] = v;
    __syncthreads();
    int add = 0;
    #pragma unroll
    for (int i = 0; i < 4; ++i) if (i < w) add += ws[i];
    if (t < nb) partial[t] = v + add - orig;   // exclusive
}

__global__ __launch_bounds__(256) void scanC_kernel(const int* __restrict__ in,
                                                    const int* __restrict__ partial,
                                                    int* __restrict__ out, int n) {
    int t = threadIdx.x, base = blockIdx.x * 1024;
    int vals[4], tsum = 0;
    #pragma unroll
    for (int j = 0; j < 4; ++j) {
        int i = base + t * 4 + j;
        vals[j] = (i < n) ? in[i] : 0;
        tsum += vals[j];
    }
    int lane = t & 63, w = t >> 6;
    int incl = tsum;
    #pragma unroll
    for (int d = 1; d < 64; d <<= 1) { int u = __shfl_up(incl, d, 64); if (lane >= d) incl += u; }
    __shared__ int ws[4];
    if (lane == 63) ws[w] = incl;
    __syncthreads();
    int add = partial[blockIdx.x];
    #pragma unroll
    for (int i = 0; i < 4; ++i) if (i < w) add += ws[i];
    int run = add + incl - tsum;
    #pragma unroll
    for (int j = 0; j < 4; ++j) {
        int i = base + t * 4 + j;
        if (i < n) out[i] = run;
        run += vals[j];
    }
}

// ---------------- F: gather segments + fine counting sort (rank-based) ----------------
__global__ __launch_bounds__(256) void fine_kernel(const uint* __restrict__ ebuf,
                                                   const int* __restrict__ histG,
                                                   const int* __restrict__ localOff,
                                                   const int* __restrict__ histS,
                                                   uint* __restrict__ csr,
                                                   int* __restrict__ deg,
                                                   int* __restrict__ offs,
                                                   float* __restrict__ dinv,
                                                   int e, int nbv, int gblk, int n) {
    __shared__ uint elist[4096];
    __shared__ uint csrl[4096];
    __shared__ int cur[BK], excl[BK];
    int b = blockIdx.x, t = threadIdx.x;
    int seg0 = histS[b * gblk];
    int seg1 = (b + 1 < nbv) ? histS[(b + 1) * gblk] : e;
    int cnt = min(seg1 - seg0, 4096);

    if (t < BK) cur[t] = 0;
    // gather this bucket's per-block segments into LDS
    for (int g = t; g < gblk; g += 256) {
        int c   = histG[b * gblk + g];
        int src = g * CHUNK + localOff[b * gblk + g];
        int dst = histS[b * gblk + g] - seg0;
        for (int i = 0; i < c; ++i) elist[dst + i] = ebuf[src + i];
    }
    __syncthreads();
    // pass 1: rank via single atomic per element (<=16 per thread, static idx)
    int rk[16];
    #pragma unroll
    for (int j = 0; j < 16; ++j) {
        int i = t + j * 256;
        if (i < cnt) rk[j] = atomicAdd(&cur[elist[i] & 127], 1);
    }
    __syncthreads();
    if (t < 64) {                       // exclusive scan of 128 bins, wave 0
        int v0 = cur[2 * t], v1 = cur[2 * t + 1];
        int s = v0 + v1, incl = s;
        #pragma unroll
        for (int d = 1; d < 64; d <<= 1) { int u = __shfl_up(incl, d, 64); if (t >= d) incl += u; }
        int base = incl - s;
        excl[2 * t] = base; excl[2 * t + 1] = base + v0;
    }
    __syncthreads();
    // pass 2: place without atomics
    #pragma unroll
    for (int j = 0; j < 16; ++j) {
        int i = t + j * 256;
        if (i < cnt) {
            uint v = elist[i];
            int d = v & 127;
            csrl[excl[d] + rk[j]] = v >> 7;
        }
    }
    __syncthreads();
    for (int i = t; i < cnt; i += 256) csr[seg0 + i] = csrl[i];   // coalesced
    if (t < BK) {
        int node = b * BK + t;
        if (node < n) {
            int dg = cur[t];
            deg[node]  = dg;
            offs[node] = seg0 + excl[t];
            dinv[node] = rsqrtf((float)(dg + 1));
        }
    }
}

// ---------------- GEMM: hsb8 = int8( (x @ W) * dinv[row] / rowscale ), MFMA 16x16x32
// rowscale = rowmax/127 via LDS atomicMax; stored in hscale[row]. ----------------

constexpr int MT = 64;
constexpr int XS_STRIDE = 264;

__global__ __launch_bounds__(256) void gemm_kernel(const float* __restrict__ x,
                                                   const ushort* __restrict__ Wt,
                                                   const float* __restrict__ dinv,
                                                   char* __restrict__ hsb8,
                                                   float* __restrict__ hscale, int n) {
    __shared__ ushort xs[MT * XS_STRIDE];
    __shared__ float sdinv[MT];
    __shared__ uint rmaxs[16];
    int t = threadIdx.x, lane = t & 63, w = t >> 6;
    int row0 = blockIdx.x * MT;

    bf16x8 bfrag[8][2];
    #pragma unroll
    for (int c = 0; c < 8; ++c)
        #pragma unroll
        for (int f = 0; f < 2; ++f)
            bfrag[c][f] = *(const bf16x8*)(Wt + (size_t)(((c * 8) + (w * 2 + f)) * 64 + lane) * 8);

    #pragma unroll
    for (int i = 0; i < 16; ++i) {
        int rl = w * 16 + i;
        int gr = row0 + rl; if (gr >= n) gr = n - 1;
        float4 v = *(const float4*)(x + (size_t)gr * KDIM + lane * 4);
        ushort4 o;
        o.x = f2bf(v.x); o.y = f2bf(v.y); o.z = f2bf(v.z); o.w = f2bf(v.w);
        *(ushort4*)(xs + rl * XS_STRIDE + lane * 4) = o;
    }
    if (t < MT) { int g = row0 + t; sdinv[t] = dinv[(g < n) ? g : (n - 1)]; }
    __syncthreads();

    for (int s = 0; s < MT / 16; ++s) {
        f32x4 acc0 = {0.f, 0.f, 0.f, 0.f}, acc1 = {0.f, 0.f, 0.f, 0.f};
        #pragma unroll
        for (int c = 0; c < 8; ++c) {
            const ushort* ap = xs + (s * 16 + (lane & 15)) * XS_STRIDE + c * 32 + (lane >> 4) * 8;
            bf16x8 afrag = *(const bf16x8*)ap;
            acc0 = __builtin_amdgcn_mfma_f32_16x16x32_bf16(afrag, bfrag[c][0], acc0, 0, 0, 0);
            acc1 = __builtin_amdgcn_mfma_f32_16x16x32_bf16(afrag, bfrag[c][1], acc1, 0, 0, 0);
        }
        // ---- per-row absmax reduction ----
        if (t < 16) rmaxs[t] = 0;
        __syncthreads();
        float v0[4], v1[4];
        #pragma unroll
        for (int reg = 0; reg < 4; ++reg) {
            int rl = s * 16 + (lane >> 4) * 4 + reg;
            int gr = row0 + rl;
            if (gr < n) {
                float d = sdinv[rl];
                v0[reg] = acc0[reg] * d;
                v1[reg] = acc1[reg] * d;
                float m = fmaxf(fabsf(v0[reg]), fabsf(v1[reg]));
                atomicMax(&rmaxs[(lane >> 4) * 4 + reg], __float_as_uint(m));
            }
        }
        __syncthreads();
        // ---- quantize + store ----
        #pragma unroll
        for (int reg = 0; reg < 4; ++reg) {
            int rl = s * 16 + (lane >> 4) * 4 + reg;
            int gr = row0 + rl;
            if (gr < n) {
                float rm = __uint_as_float(rmaxs[(lane >> 4) * 4 + reg]);
                float inv = (rm > 0.f) ? 127.f / rm : 0.f;
                int q0 = __float2int_rn(v0[reg] * inv);
                int q1 = __float2int_rn(v1[reg] * inv);
                int col0 = w * 32 + (lane & 15);
                hsb8[(size_t)gr * HDIM + col0]      = (char)q0;
                hsb8[(size_t)gr * HDIM + col0 + 16] = (char)q1;
            }
        }
        if (t < 16) {
            int gr = row0 + s * 16 + t;
            if (gr < n) hscale[gr] = __uint_as_float(rmaxs[t]) * (1.f / 127.f);
        }
        __syncthreads();
    }
}

// ---------------- aggregation (R8-proven, unchanged): int8 rows (128B = 1 line),
// per-row scale, 4 nodes/wave, 16-lane group per node, 16-ahead csr index load,
// 8-deep gather batches, nontemporal csr/out streams. ----------------
__global__ __launch_bounds__(256) void aggregate_kernel(
    const char* __restrict__ hsb8, const float* __restrict__ hscale,
    const int* __restrict__ offs, const int* __restrict__ deg,
    const uint* __restrict__ csr, const float* __restrict__ dinv,
    const float* __restrict__ b, const float* __restrict__ alpha,
    float* __restrict__ out, int n) {
    int wv = threadIdx.x >> 6, lane = threadIdx.x & 63;
    int grp = lane >> 4, li = lane & 15;
    int node = blockIdx.x * 16 + wv * 4 + grp;
    bool valid = node < n;
    int nd   = valid ? node : n;            // n = zero row (scale 0)
    int base = valid ? offs[node] : 0;
    int cnt  = valid ? deg[node] : 0;
    const uint2* hs2 = (const uint2*)hsb8;  // row = 16 x uint2, lane li owns 8 ch

    float a[8];
    #pragma unroll
    for (int i = 0; i < 8; ++i) a[i] = 0.f;

    uint2 su = hs2[(size_t)nd * 16 + li];   // self loop
    acc8i(a, su, hscale[nd]);

    for (int it = 0; it < cnt; it += 16) {
        // one coalesced 16-wide index load covers the average degree
        int src_l = (it + li < cnt) ? (int)__builtin_nontemporal_load(csr + base + it + li) : n;

        // batch A: edges it..it+7, 8 gathers in flight
        int sA[8];
        #pragma unroll
        for (int k = 0; k < 8; ++k) sA[k] = __shfl(src_l, grp * 16 + k, 64);
        uint2 uA[8];
        float scA[8];
        #pragma unroll
        for (int k = 0; k < 8; ++k) uA[k] = hs2[(size_t)sA[k] * 16 + li];
        #pragma unroll
        for (int k = 0; k < 8; ++k) scA[k] = hscale[sA[k]];
        #pragma unroll
        for (int k = 0; k < 8; ++k) acc8i(a, uA[k], scA[k]);

        // batch B: edges it+8..it+15 (skip entirely when degree exhausted)
        if (it + 8 < cnt) {
            int sB[8];
            #pragma unroll
            for (int k = 0; k < 8; ++k) sB[k] = __shfl(src_l, grp * 16 + 8 + k, 64);
            uint2 uB[8];
            float scB[8];
            #pragma unroll
            for (int k = 0; k < 8; ++k) uB[k] = hs2[(size_t)sB[k] * 16 + li];
            #pragma unroll
            for (int k = 0; k < 8; ++k) scB[k] = hscale[sB[k]];
            #pragma unroll
            for (int k = 0; k < 8; ++k) acc8i(a, uB[k], scB[k]);
        }
    }

    if (valid) {
        float dc = dinv[node];
        int c0 = li * 8;
        float o[8];
        #pragma unroll
        for (int i = 0; i < 8; ++i) {
            float v = fmaf(dc, a[i], b[c0 + i]);
            o[i] = v >= 0.f ? v : alpha[c0 + i] * v;
        }
        float* op = out + (size_t)node * HDIM + c0;
        f32x4 v0 = {o[0], o[1], o[2], o[3]};
        f32x4 v1 = {o[4], o[5], o[6], o[7]};
        __builtin_nontemporal_store(v0, (f32x4*)op);
        __builtin_nontemporal_store(v1, (f32x4*)(op + 4));
    }
}

// ---------------- launch ----------------

extern "C" void kernel_launch(void* const* d_in, const int* in_sizes, int n_in,
                              void* d_out, int out_size, void* d_ws, size_t ws_size,
                              hipStream_t stream) {
    const float* x     = (const float*)d_in[0];
    const int*   ei    = (const int*)d_in[1];
    const float* W     = (const float*)d_in[2];
    const float* b     = (const float*)d_in[3];
    const float* alpha = (const float*)d_in[4];
    float* out = (float*)d_out;

    int E = in_sizes[1] / 2;
    int N = in_sizes[0] / KDIM;
    int NB = (N + BK - 1) / BK;                // coarse buckets (782)
    int GBLK = (E + CHUNK - 1) / CHUNK;        // sort blocks (196)
    int SCAN_N = NB * GBLK;

    // ws: hsb8 int8[(N+1)*128] | hscale f32[N+1] | Wt bf16[32768] | dinv f32[N]
    //   | deg int[N] | offs int[N] | histG int[SCAN_N] | localOff int[SCAN_N]
    //   | histS int[SCAN_N] | partial int[512] | ebuf uint[GBLK*CHUNK] | csr uint[E]
    char*  hsb8   = (char*)d_ws;
    float* hscale = (float*)(hsb8 + (size_t)(N + 1) * HDIM);
    ushort* Wt    = (ushort*)(hscale + (N + 1));
    float* dinv   = (float*)(Wt + 32768);
    int* deg      = (int*)(dinv + N);
    int* offs     = deg + N;
    int* histG    = offs + N;
    int* localOff = histG + SCAN_N;
    int* histS    = localOff + SCAN_N;
    int* partial  = histS + SCAN_N;
    uint* ebuf    = (uint*)(partial + 512);
    uint* csr     = ebuf + (size_t)GBLK * CHUNK;

    const int* rowp = ei;      // sources
    const int* colp = ei + E;  // destinations

    int nbScan = (SCAN_N + 1023) / 1024;

    hipLaunchKernelGGL(prep_sort_kernel, dim3(9 + GBLK), dim3(512), 0, stream,
                       W, Wt, hsb8, hscale, rowp, colp, ebuf, histG, localOff, N, E, NB, GBLK);
    hipLaunchKernelGGL(scanA_kernel, dim3(nbScan), dim3(256), 0, stream, histG, partial, SCAN_N);
    hipLaunchKernelGGL(scanB_kernel, dim3(1), dim3(256), 0, stream, partial, nbScan);
    hipLaunchKernelGGL(scanC_kernel, dim3(nbScan), dim3(256), 0, stream, histG, partial, histS, SCAN_N);
    hipLaunchKernelGGL(fine_kernel, dim3(NB), dim3(256), 0, stream,
                       ebuf, histG, localOff, histS, csr, deg, offs, dinv, E, NB, GBLK, N);
    hipLaunchKernelGGL(gemm_kernel, dim3((N + MT - 1) / MT), dim3(256), 0, stream,
                       x, Wt, dinv, hsb8, hscale, N);
    hipLaunchKernelGGL(aggregate_kernel, dim3((N + 15) / 16), dim3(256), 0, stream,
                       hsb8, hscale, offs, deg, csr, dinv, b, alpha, out, N);
}